// Round 10
// baseline (340.844 us; speedup 1.0000x reference)
//
#include <hip/hip_runtime.h>
#include <hip/hip_bf16.h>
#include <stdint.h>

#define Bsz 2
#define Sq  2048
#define HID 1024
#define NH  16
#define HD  64

typedef __attribute__((ext_vector_type(8))) short bf16x8;
typedef __attribute__((ext_vector_type(4))) float f32x4;

__device__ __forceinline__ void gload16(const void* g, void* l) {
  __builtin_amdgcn_global_load_lds((const __attribute__((address_space(1))) void*)g,
                                   (__attribute__((address_space(3))) void*)l, 16, 0, 0);
}

// ---------------- cast fp32 -> bf16 (vectorized) ----------------
__global__ void cast_bf16_k(const float* __restrict__ src, __hip_bfloat16* __restrict__ dst, int n4) {
  int i = blockIdx.x * blockDim.x + threadIdx.x;
  if (i >= n4) return;
  float4 v = reinterpret_cast<const float4*>(src)[i];
  union { ushort4 u; __hip_bfloat16 h[4]; } o;
  o.h[0] = __float2bfloat16(v.x);
  o.h[1] = __float2bfloat16(v.y);
  o.h[2] = __float2bfloat16(v.z);
  o.h[3] = __float2bfloat16(v.w);
  reinterpret_cast<ushort4*>(dst)[i] = o.u;
}

// ---------------- bf16 MFMA GEMM: C = A * W^T + bias ----------------
// A: [M,K] bf16 row-major. W: [N,K] bf16 row-major (nn.Linear weight layout).
// MODE 0: Ntot=3072 fused QKV; W/bias/dst selected by column block; dst fp32 [B,H,S,D].
// MODE 1: N=1024; flat fp32 store D0[row*HID + col].
template<int MODE>
__global__ __launch_bounds__(256)
void gemm_bt(const __hip_bfloat16* __restrict__ A,
             const __hip_bfloat16* __restrict__ W0, const __hip_bfloat16* __restrict__ W1,
             const __hip_bfloat16* __restrict__ W2,
             const float* __restrict__ bias0, const float* __restrict__ bias1,
             const float* __restrict__ bias2,
             float* __restrict__ D0, float* __restrict__ D1, float* __restrict__ D2,
             int K)
{
  __shared__ __align__(16) __hip_bfloat16 sA[128 * 32];
  __shared__ __align__(16) __hip_bfloat16 sB[128 * 32];

  const int tid  = threadIdx.x;
  const int wave = tid >> 6, lane = tid & 63;
  const int lane16 = lane & 15, lgrp = lane >> 4;
  const int wr = wave >> 1, wc = wave & 1;

  const int bn = blockIdx.x * 128;
  const int bm = blockIdx.y * 128;

  const __hip_bfloat16* Wsel;
  const float* bsel;
  int nbase;
  if (MODE == 0) {
    int sel = bn >> 10;
    Wsel  = (sel == 0) ? W0 : (sel == 1 ? W1 : W2);
    bsel  = (sel == 0) ? bias0 : (sel == 1 ? bias1 : bias2);
    nbase = bn & 1023;
  } else {
    Wsel = W0; bsel = bias0; nbase = bn;
  }

  f32x4 acc[4][4];
  #pragma unroll
  for (int m = 0; m < 4; ++m)
    #pragma unroll
    for (int n = 0; n < 4; ++n)
      acc[m][n] = (f32x4){0.f, 0.f, 0.f, 0.f};

  // staging geometry: tile 128x32 bf16 = 4096 elems = 8 chunks of 512 elems (1KB);
  // wave w stages chunks 2w, 2w+1; lane writes 16B at chunk_base + lane*16.
  const int c0 = wave * 2, c1 = wave * 2 + 1;
  const int e0 = c0 * 512 + lane * 8;
  const int e1 = c1 * 512 + lane * 8;
  const int r0 = e0 >> 5, q0 = e0 & 31;
  const int r1 = e1 >> 5, q1 = e1 & 31;

  for (int k0 = 0; k0 < K; k0 += 32) {
    __syncthreads();
    gload16(A    + (size_t)(bm    + r0) * K + k0 + q0, &sA[c0 * 512]);
    gload16(A    + (size_t)(bm    + r1) * K + k0 + q1, &sA[c1 * 512]);
    gload16(Wsel + (size_t)(nbase + r0) * K + k0 + q0, &sB[c0 * 512]);
    gload16(Wsel + (size_t)(nbase + r1) * K + k0 + q1, &sB[c1 * 512]);
    __syncthreads();

    bf16x8 af[4], bfv[4];
    #pragma unroll
    for (int m = 0; m < 4; ++m)
      af[m] = *reinterpret_cast<const bf16x8*>(&sA[(wr * 64 + m * 16 + lane16) * 32 + lgrp * 8]);
    #pragma unroll
    for (int n = 0; n < 4; ++n)
      bfv[n] = *reinterpret_cast<const bf16x8*>(&sB[(wc * 64 + n * 16 + lane16) * 32 + lgrp * 8]);
    #pragma unroll
    for (int m = 0; m < 4; ++m)
      #pragma unroll
      for (int n = 0; n < 4; ++n)
        acc[m][n] = __builtin_amdgcn_mfma_f32_16x16x32_bf16(af[m], bfv[n], acc[m][n], 0, 0, 0);
  }

  // epilogue: C/D layout col = lane&15, row = (lane>>4)*4 + e
  #pragma unroll
  for (int m = 0; m < 4; ++m) {
    #pragma unroll
    for (int n = 0; n < 4; ++n) {
      int colg = bn + wc * 64 + n * 16 + lane16;
      int cloc = (MODE == 0) ? (colg & 1023) : colg;
      float bv = bsel[cloc];
      #pragma unroll
      for (int e = 0; e < 4; ++e) {
        int rowg  = bm + wr * 64 + m * 16 + lgrp * 4 + e;
        float val = acc[m][n][e] + bv;
        if (MODE == 0) {
          int sel = colg >> 10;
          float* Ds = (sel == 0) ? D0 : (sel == 1 ? D1 : D2);
          int b = rowg >> 11, sl = rowg & 2047;
          int h = cloc >> 6, d = cloc & 63;
          Ds[(((size_t)(b * NH + h)) * Sq + sl) * HD + d] = val;
        } else {
          D0[(size_t)rowg * HID + colg] = val;
        }
      }
    }
  }
}

// ---------------- sparse attention ----------------
// mask: allowed j for row i: j in {0} U [i-64, i]  (<=66 columns)
// one wave per query row; 4 rows per block; q,k,v fp32 [B,H,S,D]; out bf16 [B*S, HID]
__global__ __launch_bounds__(256)
void sparse_attn(const float* __restrict__ q, const float* __restrict__ k,
                 const float* __restrict__ v, __hip_bfloat16* __restrict__ out)
{
  const int wave = threadIdx.x >> 6, lane = threadIdx.x & 63;
  const int bh = blockIdx.x >> 9;          // / (S/4 = 512)
  const int i  = ((blockIdx.x & 511) << 2) + wave;

  const float* qh = q + (size_t)bh * Sq * HD;
  const float* kh = k + (size_t)bh * Sq * HD;
  const float* vh = v + (size_t)bh * Sq * HD;

  __shared__ __align__(16) float sq[4][64];
  __shared__ float sp[4][66];

  sq[wave][lane] = qh[(size_t)i * HD + lane];
  __syncthreads();

  const float4* sqv = reinterpret_cast<const float4*>(sq[wave]);

  // main columns: lane l -> j = i - l  (covers [i-63, i])
  int j1 = i - lane;
  float s1 = -INFINITY;
  if (j1 >= 0) {
    const float4* kr = reinterpret_cast<const float4*>(kh + (size_t)j1 * HD);
    float acc = 0.f;
    #pragma unroll
    for (int c = 0; c < 16; ++c) {
      float4 qv = sqv[c];
      float4 kv = kr[c];
      acc += qv.x * kv.x + qv.y * kv.y + qv.z * kv.z + qv.w * kv.w;
    }
    s1 = acc * 0.125f;
  }
  // extras: lane0 -> j = i-64 (if >=0); lane1 -> j = 0 (if i-64 > 0, else covered)
  int je = -1;
  if (lane == 0 && i - 64 >= 0) je = i - 64;
  if (lane == 1 && i - 64 > 0)  je = 0;
  float se = -INFINITY;
  if (je >= 0) {
    const float4* kr = reinterpret_cast<const float4*>(kh + (size_t)je * HD);
    float acc = 0.f;
    #pragma unroll
    for (int c = 0; c < 16; ++c) {
      float4 qv = sqv[c];
      float4 kv = kr[c];
      acc += qv.x * kv.x + qv.y * kv.y + qv.z * kv.z + qv.w * kv.w;
    }
    se = acc * 0.125f;
  }

  // wave softmax over {s1 lanes} U {se lanes 0,1}
  float mx = fmaxf(s1, se);
  #pragma unroll
  for (int off = 32; off; off >>= 1) mx = fmaxf(mx, __shfl_xor(mx, off));
  float p1 = (j1 >= 0) ? __expf(s1 - mx) : 0.f;
  float pe = (je >= 0) ? __expf(se - mx) : 0.f;
  float sm = p1 + pe;
  #pragma unroll
  for (int off = 32; off; off >>= 1) sm += __shfl_xor(sm, off);
  float inv = 1.f / sm;

  sp[wave][lane] = p1 * inv;
  if (lane == 0) sp[wave][64] = pe * inv;
  if (lane == 1) sp[wave][65] = pe * inv;
  __syncthreads();

  // PV: lane = dim d
  float o = 0.f;
  int tmax = (i < 63) ? i : 63;
  for (int t = 0; t <= tmax; ++t) {
    int j = i - t;
    o += sp[wave][t] * vh[(size_t)j * HD + lane];
  }
  if (i >= 64) o += sp[wave][64] * vh[(size_t)(i - 64) * HD + lane];
  if (i > 64)  o += sp[wave][65] * vh[lane];

  const int b = bh >> 4, h = bh & 15;
  size_t srow = (size_t)b * Sq + i;
  out[srow * HID + h * HD + lane] = __float2bfloat16(o);
}

// ---------------- launch ----------------
extern "C" void kernel_launch(void* const* d_in, const int* in_sizes, int n_in,
                              void* d_out, int out_size, void* d_ws, size_t ws_size,
                              hipStream_t stream) {
  const float* hs = (const float*)d_in[0];
  const float* Wq = (const float*)d_in[1];
  const float* bq = (const float*)d_in[2];
  const float* Wk = (const float*)d_in[3];
  const float* bk = (const float*)d_in[4];
  const float* Wv = (const float*)d_in[5];
  const float* bv = (const float*)d_in[6];
  const float* Wo = (const float*)d_in[7];
  const float* bo = (const float*)d_in[8];

  char* ws = (char*)d_ws;
  __hip_bfloat16* Xbf = (__hip_bfloat16*)(ws);                 //  8,388,608 B
  __hip_bfloat16* Wqb = (__hip_bfloat16*)(ws + 8388608);       //  2,097,152
  __hip_bfloat16* Wkb = (__hip_bfloat16*)(ws + 10485760);      //  2,097,152
  __hip_bfloat16* Wvb = (__hip_bfloat16*)(ws + 12582912);      //  2,097,152
  __hip_bfloat16* Wob = (__hip_bfloat16*)(ws + 14680064);      //  2,097,152
  float*          qf  = (float*)(ws + 16777216);               // 16,777,216
  float*          kf  = (float*)(ws + 33554432);               // 16,777,216
  float*          vf  = (float*)(ws + 50331648);               // 16,777,216
  __hip_bfloat16* att = (__hip_bfloat16*)(ws + 67108864);      //  8,388,608  (total 75,497,472)

  // casts
  cast_bf16_k<<<4096, 256, 0, stream>>>(hs, Xbf, (Bsz * Sq * HID) / 4);
  cast_bf16_k<<<1024, 256, 0, stream>>>(Wq, Wqb, (HID * HID) / 4);
  cast_bf16_k<<<1024, 256, 0, stream>>>(Wk, Wkb, (HID * HID) / 4);
  cast_bf16_k<<<1024, 256, 0, stream>>>(Wv, Wvb, (HID * HID) / 4);
  cast_bf16_k<<<1024, 256, 0, stream>>>(Wo, Wob, (HID * HID) / 4);

  // fused QKV projection: [4096,1024] x [3072,1024]^T
  dim3 g1(3 * HID / 128, (Bsz * Sq) / 128);
  gemm_bt<0><<<g1, 256, 0, stream>>>(Xbf, Wqb, Wkb, Wvb, bq, bk, bv, qf, kf, vf, HID);

  // sparse attention
  sparse_attn<<<(Bsz * NH * Sq) / 4, 256, 0, stream>>>(qf, kf, vf, att);

  // output projection: [4096,1024] x [1024,1024]^T -> fp32 d_out
  dim3 g2(HID / 128, (Bsz * Sq) / 128);
  gemm_bt<1><<<g2, 256, 0, stream>>>(att, Wob, nullptr, nullptr, bo, nullptr, nullptr,
                                     (float*)d_out, nullptr, nullptr, HID);
}

// Round 11
// 176.443 us; speedup vs baseline: 1.9318x; 1.9318x over previous
//
#include <hip/hip_runtime.h>
#include <hip/hip_bf16.h>
#include <stdint.h>

#define Bsz 2
#define Sq  2048
#define HID 1024
#define NH  16
#define HD  64

// attention tiling
#define QB 64        // queries per block
#define KR 160       // K/V LDS rows: 0..127 = band, 128 = global row 0, 129..159 = zero
#define KP 72        // K row stride in bf16 elems (16B-aligned frags, bank-spread)
#define VP 168       // VT / P row stride in bf16 elems (16B-aligned, bank-spread)

typedef __attribute__((ext_vector_type(8))) short bf16x8;
typedef __attribute__((ext_vector_type(4))) float f32x4;

__device__ __forceinline__ void gload16(const void* g, void* l) {
  __builtin_amdgcn_global_load_lds((const __attribute__((address_space(1))) void*)g,
                                   (__attribute__((address_space(3))) void*)l, 16, 0, 0);
}

// ---------------- cast fp32 -> bf16 (vectorized) ----------------
__global__ void cast_bf16_k(const float* __restrict__ src, __hip_bfloat16* __restrict__ dst, int n4) {
  int i = blockIdx.x * blockDim.x + threadIdx.x;
  if (i >= n4) return;
  float4 v = reinterpret_cast<const float4*>(src)[i];
  union { ushort4 u; __hip_bfloat16 h[4]; } o;
  o.h[0] = __float2bfloat16(v.x);
  o.h[1] = __float2bfloat16(v.y);
  o.h[2] = __float2bfloat16(v.z);
  o.h[3] = __float2bfloat16(v.w);
  reinterpret_cast<ushort4*>(dst)[i] = o.u;
}

// ---------------- bf16 MFMA GEMM: C = A * W^T + bias ----------------
// MODE 0: Ntot=3072 fused QKV; dst BF16 [B,H,S,D] (q,k,v).
// MODE 1: N=1024; flat fp32 store to d_out.
template<int MODE>
__global__ __launch_bounds__(256)
void gemm_bt(const __hip_bfloat16* __restrict__ A,
             const __hip_bfloat16* __restrict__ W0, const __hip_bfloat16* __restrict__ W1,
             const __hip_bfloat16* __restrict__ W2,
             const float* __restrict__ bias0, const float* __restrict__ bias1,
             const float* __restrict__ bias2,
             void* __restrict__ D0v, void* __restrict__ D1v, void* __restrict__ D2v,
             int K)
{
  __shared__ __align__(16) __hip_bfloat16 sA[128 * 32];
  __shared__ __align__(16) __hip_bfloat16 sB[128 * 32];

  const int tid  = threadIdx.x;
  const int wave = tid >> 6, lane = tid & 63;
  const int lane16 = lane & 15, lgrp = lane >> 4;
  const int wr = wave >> 1, wc = wave & 1;

  const int bn = blockIdx.x * 128;
  const int bm = blockIdx.y * 128;

  const __hip_bfloat16* Wsel;
  const float* bsel;
  int nbase;
  if (MODE == 0) {
    int sel = bn >> 10;
    Wsel  = (sel == 0) ? W0 : (sel == 1 ? W1 : W2);
    bsel  = (sel == 0) ? bias0 : (sel == 1 ? bias1 : bias2);
    nbase = bn & 1023;
  } else {
    Wsel = W0; bsel = bias0; nbase = bn;
  }

  f32x4 acc[4][4];
  #pragma unroll
  for (int m = 0; m < 4; ++m)
    #pragma unroll
    for (int n = 0; n < 4; ++n)
      acc[m][n] = (f32x4){0.f, 0.f, 0.f, 0.f};

  const int c0 = wave * 2, c1 = wave * 2 + 1;
  const int e0 = c0 * 512 + lane * 8;
  const int e1 = c1 * 512 + lane * 8;
  const int r0 = e0 >> 5, q0 = e0 & 31;
  const int r1 = e1 >> 5, q1 = e1 & 31;

  for (int k0 = 0; k0 < K; k0 += 32) {
    __syncthreads();
    gload16(A    + (size_t)(bm    + r0) * K + k0 + q0, &sA[c0 * 512]);
    gload16(A    + (size_t)(bm    + r1) * K + k0 + q1, &sA[c1 * 512]);
    gload16(Wsel + (size_t)(nbase + r0) * K + k0 + q0, &sB[c0 * 512]);
    gload16(Wsel + (size_t)(nbase + r1) * K + k0 + q1, &sB[c1 * 512]);
    __syncthreads();

    bf16x8 af[4], bfv[4];
    #pragma unroll
    for (int m = 0; m < 4; ++m)
      af[m] = *reinterpret_cast<const bf16x8*>(&sA[(wr * 64 + m * 16 + lane16) * 32 + lgrp * 8]);
    #pragma unroll
    for (int n = 0; n < 4; ++n)
      bfv[n] = *reinterpret_cast<const bf16x8*>(&sB[(wc * 64 + n * 16 + lane16) * 32 + lgrp * 8]);
    #pragma unroll
    for (int m = 0; m < 4; ++m)
      #pragma unroll
      for (int n = 0; n < 4; ++n)
        acc[m][n] = __builtin_amdgcn_mfma_f32_16x16x32_bf16(af[m], bfv[n], acc[m][n], 0, 0, 0);
  }

  // epilogue: C/D layout col = lane&15, row = (lane>>4)*4 + e
  #pragma unroll
  for (int m = 0; m < 4; ++m) {
    #pragma unroll
    for (int n = 0; n < 4; ++n) {
      int colg = bn + wc * 64 + n * 16 + lane16;
      int cloc = (MODE == 0) ? (colg & 1023) : colg;
      float bv = bsel[cloc];
      #pragma unroll
      for (int e = 0; e < 4; ++e) {
        int rowg  = bm + wr * 64 + m * 16 + lgrp * 4 + e;
        float val = acc[m][n][e] + bv;
        if (MODE == 0) {
          int sel = colg >> 10;
          __hip_bfloat16* Ds = (sel == 0) ? (__hip_bfloat16*)D0v
                              : (sel == 1 ? (__hip_bfloat16*)D1v : (__hip_bfloat16*)D2v);
          int b = rowg >> 11, sl = rowg & 2047;
          int h = cloc >> 6, d = cloc & 63;
          Ds[(((size_t)(b * NH + h)) * Sq + sl) * HD + d] = __float2bfloat16(val);
        } else {
          ((float*)D0v)[(size_t)rowg * HID + colg] = val;
        }
      }
    }
  }
}

// ---------------- MFMA sparse attention ----------------
// Block = one head-instance x 64 queries. Band K rows [i0-64, i0+63] at LDS r=0..127
// (j = i0-64+r), global row 0 at r=128, r=129..159 zero. Per wave: 16 queries.
// QK^T and PV via mfma_f32_16x16x32_bf16. Mask: (r>=qi && r<=qi+64 && j>=0) | (r==128 && i>64).
__global__ __launch_bounds__(256)
void sparse_attn_mfma(const __hip_bfloat16* __restrict__ qg,
                      const __hip_bfloat16* __restrict__ kg,
                      const __hip_bfloat16* __restrict__ vg,
                      __hip_bfloat16* __restrict__ out)
{
  // sKP: K band during QK phase, then reused for P tiles during PV phase (barrier between).
  __shared__ __align__(16) unsigned short sKP[KR * KP];   // 23040 B  (>= 4*16*VP = 21504 B for P)
  __shared__ __align__(16) unsigned short sVT[HD * VP];   // 21504 B

  const int tid = threadIdx.x;
  const int w   = tid >> 6, lane = tid & 63;
  const int l16 = lane & 15, lg = lane >> 4;
  const int bid = blockIdx.x;
  const int bh  = bid >> 5;           // 0..31  (b*NH + h)
  const int qb  = bid & 31;
  const int i0  = qb * QB;

  const __hip_bfloat16* qh = qg + (size_t)bh * Sq * HD;
  const __hip_bfloat16* kh = kg + (size_t)bh * Sq * HD;
  const __hip_bfloat16* vh = vg + (size_t)bh * Sq * HD;

  // ---- stage: K row-major into sKP, V transposed into sVT (zeros where j invalid) ----
  // 160 rows x 64 elems = 2560 chunks of 4 bf16; 10 chunks per thread.
  #pragma unroll
  for (int p = 0; p < 10; ++p) {
    int c  = p * 256 + tid;
    int r  = c >> 4, d4 = (c & 15) * 4;
    int j  = (r < 128) ? (i0 - 64 + r) : ((r == 128) ? 0 : -1);
    ushort4 kv = {0, 0, 0, 0}, vv = {0, 0, 0, 0};
    if (j >= 0) {
      kv = *reinterpret_cast<const ushort4*>(kh + (size_t)j * HD + d4);
      vv = *reinterpret_cast<const ushort4*>(vh + (size_t)j * HD + d4);
    }
    *reinterpret_cast<ushort4*>(&sKP[r * KP + d4]) = kv;   // 8B aligned: KP,d4 even
    sVT[(d4 + 0) * VP + r] = vv.x;
    sVT[(d4 + 1) * VP + r] = vv.y;
    sVT[(d4 + 2) * VP + r] = vv.z;
    sVT[(d4 + 3) * VP + r] = vv.w;
  }
  __syncthreads();

  // ---- QK^T: A = Q rows (this wave's 16 queries, direct from global), B = K LDS rows ----
  const int qi0 = w * 16;
  bf16x8 aq[2];
  #pragma unroll
  for (int ks = 0; ks < 2; ++ks)
    aq[ks] = *reinterpret_cast<const bf16x8*>(qh + (size_t)(i0 + qi0 + l16) * HD + ks * 32 + lg * 8);

  f32x4 c[10];
  #pragma unroll
  for (int n = 0; n < 10; ++n) {
    c[n] = (f32x4){0.f, 0.f, 0.f, 0.f};
    #pragma unroll
    for (int ks = 0; ks < 2; ++ks) {
      bf16x8 bk = *reinterpret_cast<const bf16x8*>(&sKP[(n * 16 + l16) * KP + ks * 32 + lg * 8]);
      c[n] = __builtin_amdgcn_mfma_f32_16x16x32_bf16(aq[ks], bk, c[n], 0, 0, 0);
    }
  }

  // ---- mask + wave-local softmax (each lane owns rows qi0+lg*4+e, cols l16 of each n-tile) ----
  float p[10][4];
  float mx[4], sm[4], inv[4];
  #pragma unroll
  for (int e = 0; e < 4; ++e) mx[e] = -INFINITY;
  #pragma unroll
  for (int n = 0; n < 10; ++n) {
    int r = n * 16 + l16;
    int jg = i0 - 64 + r;
    #pragma unroll
    for (int e = 0; e < 4; ++e) {
      int qi = qi0 + lg * 4 + e;
      bool ok = (n < 8) ? (r >= qi && r <= qi + 64 && jg >= 0)
                        : (r == 128 && (i0 + qi) > 64);
      float sv = ok ? c[n][e] * 0.125f : -INFINITY;
      p[n][e] = sv;
      mx[e] = fmaxf(mx[e], sv);
    }
  }
  #pragma unroll
  for (int off = 1; off < 16; off <<= 1)
    #pragma unroll
    for (int e = 0; e < 4; ++e)
      mx[e] = fmaxf(mx[e], __shfl_xor(mx[e], off));
  #pragma unroll
  for (int e = 0; e < 4; ++e) sm[e] = 0.f;
  #pragma unroll
  for (int n = 0; n < 10; ++n)
    #pragma unroll
    for (int e = 0; e < 4; ++e) {
      float pe = __expf(p[n][e] - mx[e]);   // exp(-inf)=0 for masked
      p[n][e] = pe;
      sm[e] += pe;
    }
  #pragma unroll
  for (int off = 1; off < 16; off <<= 1)
    #pragma unroll
    for (int e = 0; e < 4; ++e)
      sm[e] += __shfl_xor(sm[e], off);
  #pragma unroll
  for (int e = 0; e < 4; ++e) inv[e] = 1.f / sm[e];

  // ---- P -> LDS (transpose to A-fragment layout); reuse sKP region after barrier ----
  __syncthreads();                       // all waves done reading K
  unsigned short* Pw = &sKP[w * 16 * VP];
  #pragma unroll
  for (int n = 0; n < 10; ++n)
    #pragma unroll
    for (int e = 0; e < 4; ++e) {
      __hip_bfloat16 hb = __float2bfloat16(p[n][e] * inv[e]);
      Pw[(lg * 4 + e) * VP + n * 16 + l16] = *reinterpret_cast<unsigned short*>(&hb);
    }

  // ---- PV: A = P (16 q x 160 j), B = V^T (64 d x 160 j) ----
  f32x4 o[4];
  #pragma unroll
  for (int n = 0; n < 4; ++n) o[n] = (f32x4){0.f, 0.f, 0.f, 0.f};
  #pragma unroll
  for (int ks = 0; ks < 5; ++ks) {
    bf16x8 pa = *reinterpret_cast<const bf16x8*>(&Pw[l16 * VP + ks * 32 + lg * 8]);
    #pragma unroll
    for (int n = 0; n < 4; ++n) {
      bf16x8 vb = *reinterpret_cast<const bf16x8*>(&sVT[(n * 16 + l16) * VP + ks * 32 + lg * 8]);
      o[n] = __builtin_amdgcn_mfma_f32_16x16x32_bf16(pa, vb, o[n], 0, 0, 0);
    }
  }

  // ---- store: out[b*S + i][h*64 + d] bf16 ----
  const int b = bh >> 4, h = bh & 15;
  #pragma unroll
  for (int e = 0; e < 4; ++e) {
    int i = i0 + qi0 + lg * 4 + e;
    size_t base = ((size_t)(b * Sq + i)) * HID + h * HD;
    #pragma unroll
    for (int n = 0; n < 4; ++n)
      out[base + n * 16 + l16] = __float2bfloat16(o[n][e]);
  }
}

// ---------------- launch ----------------
extern "C" void kernel_launch(void* const* d_in, const int* in_sizes, int n_in,
                              void* d_out, int out_size, void* d_ws, size_t ws_size,
                              hipStream_t stream) {
  const float* hs = (const float*)d_in[0];
  const float* Wq = (const float*)d_in[1];
  const float* bq = (const float*)d_in[2];
  const float* Wk = (const float*)d_in[3];
  const float* bk = (const float*)d_in[4];
  const float* Wv = (const float*)d_in[5];
  const float* bv = (const float*)d_in[6];
  const float* Wo = (const float*)d_in[7];
  const float* bo = (const float*)d_in[8];

  char* ws = (char*)d_ws;
  __hip_bfloat16* Xbf = (__hip_bfloat16*)(ws);                 //  8 MB
  __hip_bfloat16* Wqb = (__hip_bfloat16*)(ws +  8388608);      //  2 MB
  __hip_bfloat16* Wkb = (__hip_bfloat16*)(ws + 10485760);      //  2 MB
  __hip_bfloat16* Wvb = (__hip_bfloat16*)(ws + 12582912);      //  2 MB
  __hip_bfloat16* Wob = (__hip_bfloat16*)(ws + 14680064);      //  2 MB
  __hip_bfloat16* qb  = (__hip_bfloat16*)(ws + 16777216);      //  8 MB  [B,H,S,D] bf16
  __hip_bfloat16* kb  = (__hip_bfloat16*)(ws + 25165824);      //  8 MB
  __hip_bfloat16* vb_ = (__hip_bfloat16*)(ws + 33554432);      //  8 MB
  __hip_bfloat16* att = (__hip_bfloat16*)(ws + 41943040);      //  8 MB  (total 50 MB)

  // casts
  cast_bf16_k<<<4096, 256, 0, stream>>>(hs, Xbf, (Bsz * Sq * HID) / 4);
  cast_bf16_k<<<1024, 256, 0, stream>>>(Wq, Wqb, (HID * HID) / 4);
  cast_bf16_k<<<1024, 256, 0, stream>>>(Wk, Wkb, (HID * HID) / 4);
  cast_bf16_k<<<1024, 256, 0, stream>>>(Wv, Wvb, (HID * HID) / 4);
  cast_bf16_k<<<1024, 256, 0, stream>>>(Wo, Wob, (HID * HID) / 4);

  // fused QKV projection -> bf16 [B,H,S,D]
  dim3 g1(3 * HID / 128, (Bsz * Sq) / 128);
  gemm_bt<0><<<g1, 256, 0, stream>>>(Xbf, Wqb, Wkb, Wvb, bq, bk, bv,
                                     (void*)qb, (void*)kb, (void*)vb_, HID);

  // MFMA sparse attention: 1024 blocks (32 head-instances x 32 query-tiles)
  sparse_attn_mfma<<<Bsz * NH * (Sq / QB), 256, 0, stream>>>(qb, kb, vb_, att);

  // output projection -> fp32 d_out
  dim3 g2(HID / 128, (Bsz * Sq) / 128);
  gemm_bt<1><<<g2, 256, 0, stream>>>(att, Wob, nullptr, nullptr, bo, nullptr, nullptr,
                                     d_out, nullptr, nullptr, HID);
}

// Round 13
// 163.749 us; speedup vs baseline: 2.0815x; 1.0775x over previous
//
#include <hip/hip_runtime.h>
#include <hip/hip_bf16.h>
#include <stdint.h>

#define Bsz 2
#define Sq  2048
#define HID 1024
#define NH  16
#define HD  64

// attention tiling
#define QB 64
#define KR 160
#define KP 72
#define VP 168

typedef __attribute__((ext_vector_type(8))) short bf16x8;
typedef __attribute__((ext_vector_type(4))) float f32x4;

__device__ __forceinline__ void gload16(const void* g, void* l) {
  __builtin_amdgcn_global_load_lds((const __attribute__((address_space(1))) void*)g,
                                   (__attribute__((address_space(3))) void*)l, 16, 0, 0);
}

// ---------------- fused cast fp32 -> bf16 (hs + 4 weights, one launch) ----------------
// chunk space: [0, 1048576) = hs (4M floats); then 4 x 262144 chunks for Wq,Wk,Wv,Wo.
__global__ void cast_all_k(const float* __restrict__ hs, const float* __restrict__ Wq,
                           const float* __restrict__ Wk, const float* __restrict__ Wv,
                           const float* __restrict__ Wo,
                           __hip_bfloat16* __restrict__ hsd, __hip_bfloat16* __restrict__ Wqd,
                           __hip_bfloat16* __restrict__ Wkd, __hip_bfloat16* __restrict__ Wvd,
                           __hip_bfloat16* __restrict__ Wod) {
  int c = blockIdx.x * blockDim.x + threadIdx.x;   // 8192*256 = 2097152 exactly
  const float* src; __hip_bfloat16* dst; int i;
  if (c < 1048576) { src = hs; dst = hsd; i = c; }
  else {
    int t = c - 1048576, w = t >> 18; i = t & 262143;
    src = (w == 0) ? Wq : (w == 1) ? Wk : (w == 2) ? Wv : Wo;
    dst = (w == 0) ? Wqd : (w == 1) ? Wkd : (w == 2) ? Wvd : Wod;
  }
  float4 v = reinterpret_cast<const float4*>(src)[i];
  union { ushort4 u; __hip_bfloat16 h[4]; } o;
  o.h[0] = __float2bfloat16(v.x);
  o.h[1] = __float2bfloat16(v.y);
  o.h[2] = __float2bfloat16(v.z);
  o.h[3] = __float2bfloat16(v.w);
  reinterpret_cast<ushort4*>(dst)[i] = o.u;
}

// ---------------- bf16 MFMA GEMM 128x128: QKV fused, bf16 [B,H,S,D] out ----------------
__global__ __launch_bounds__(256)
void gemm_qkv(const __hip_bfloat16* __restrict__ A,
              const __hip_bfloat16* __restrict__ W0, const __hip_bfloat16* __restrict__ W1,
              const __hip_bfloat16* __restrict__ W2,
              const float* __restrict__ bias0, const float* __restrict__ bias1,
              const float* __restrict__ bias2,
              __hip_bfloat16* __restrict__ D0, __hip_bfloat16* __restrict__ D1,
              __hip_bfloat16* __restrict__ D2, int K)
{
  __shared__ __align__(16) __hip_bfloat16 sA[128 * 32];
  __shared__ __align__(16) __hip_bfloat16 sB[128 * 32];

  const int tid  = threadIdx.x;
  const int wave = tid >> 6, lane = tid & 63;
  const int lane16 = lane & 15, lgrp = lane >> 4;
  const int wr = wave >> 1, wc = wave & 1;

  const int bn = blockIdx.x * 128;
  const int bm = blockIdx.y * 128;

  int sel = bn >> 10;
  const __hip_bfloat16* Wsel = (sel == 0) ? W0 : (sel == 1 ? W1 : W2);
  const float* bsel = (sel == 0) ? bias0 : (sel == 1 ? bias1 : bias2);
  __hip_bfloat16* Dsel = (sel == 0) ? D0 : (sel == 1 ? D1 : D2);
  int nbase = bn & 1023;

  f32x4 acc[4][4];
  #pragma unroll
  for (int m = 0; m < 4; ++m)
    #pragma unroll
    for (int n = 0; n < 4; ++n)
      acc[m][n] = (f32x4){0.f, 0.f, 0.f, 0.f};

  const int c0 = wave * 2, c1 = wave * 2 + 1;
  const int e0 = c0 * 512 + lane * 8;
  const int e1 = c1 * 512 + lane * 8;
  const int r0 = e0 >> 5, q0 = e0 & 31;
  const int r1 = e1 >> 5, q1 = e1 & 31;

  for (int k0 = 0; k0 < K; k0 += 32) {
    __syncthreads();
    gload16(A    + (size_t)(bm    + r0) * K + k0 + q0, &sA[c0 * 512]);
    gload16(A    + (size_t)(bm    + r1) * K + k0 + q1, &sA[c1 * 512]);
    gload16(Wsel + (size_t)(nbase + r0) * K + k0 + q0, &sB[c0 * 512]);
    gload16(Wsel + (size_t)(nbase + r1) * K + k0 + q1, &sB[c1 * 512]);
    __syncthreads();

    bf16x8 af[4], bfv[4];
    #pragma unroll
    for (int m = 0; m < 4; ++m)
      af[m] = *reinterpret_cast<const bf16x8*>(&sA[(wr * 64 + m * 16 + lane16) * 32 + lgrp * 8]);
    #pragma unroll
    for (int n = 0; n < 4; ++n)
      bfv[n] = *reinterpret_cast<const bf16x8*>(&sB[(wc * 64 + n * 16 + lane16) * 32 + lgrp * 8]);
    #pragma unroll
    for (int m = 0; m < 4; ++m)
      #pragma unroll
      for (int n = 0; n < 4; ++n)
        acc[m][n] = __builtin_amdgcn_mfma_f32_16x16x32_bf16(af[m], bfv[n], acc[m][n], 0, 0, 0);
  }

  #pragma unroll
  for (int m = 0; m < 4; ++m) {
    #pragma unroll
    for (int n = 0; n < 4; ++n) {
      int colg = bn + wc * 64 + n * 16 + lane16;
      int cloc = colg & 1023;
      float bv = bsel[cloc];
      int h = cloc >> 6, d = cloc & 63;
      #pragma unroll
      for (int e = 0; e < 4; ++e) {
        int rowg = bm + wr * 64 + m * 16 + lgrp * 4 + e;
        int b = rowg >> 11, sl = rowg & 2047;
        Dsel[(((size_t)(b * NH + h)) * Sq + sl) * HD + d] = __float2bfloat16(acc[m][n][e] + bv);
      }
    }
  }
}

// ---------------- bf16 MFMA GEMM 64x64: O-projection, fp32 out ----------------
// grid (N/64=16, M/64=64) = 1024 blocks -> 4 blocks/CU for latency overlap.
__global__ __launch_bounds__(256)
void gemm_o64(const __hip_bfloat16* __restrict__ A, const __hip_bfloat16* __restrict__ W,
              const float* __restrict__ bias, float* __restrict__ D, int K)
{
  __shared__ __align__(16) __hip_bfloat16 sA[64 * 32];
  __shared__ __align__(16) __hip_bfloat16 sB[64 * 32];

  const int tid  = threadIdx.x;
  const int wave = tid >> 6, lane = tid & 63;
  const int lane16 = lane & 15, lgrp = lane >> 4;
  const int wr = wave >> 1, wc = wave & 1;

  const int bn = blockIdx.x * 64;
  const int bm = blockIdx.y * 64;

  f32x4 acc[2][2];
  #pragma unroll
  for (int m = 0; m < 2; ++m)
    #pragma unroll
    for (int n = 0; n < 2; ++n)
      acc[m][n] = (f32x4){0.f, 0.f, 0.f, 0.f};

  // staging: tile 64x32 bf16 = 2048 elems = 4 chunks of 512; wave w stages chunk w.
  const int e0 = wave * 512 + lane * 8;
  const int r0 = e0 >> 5, q0 = e0 & 31;

  for (int k0 = 0; k0 < K; k0 += 32) {
    __syncthreads();
    gload16(A + (size_t)(bm + r0) * K + k0 + q0, &sA[wave * 512]);
    gload16(W + (size_t)(bn + r0) * K + k0 + q0, &sB[wave * 512]);
    __syncthreads();

    bf16x8 af[2], bfv[2];
    #pragma unroll
    for (int m = 0; m < 2; ++m)
      af[m] = *reinterpret_cast<const bf16x8*>(&sA[(wr * 32 + m * 16 + lane16) * 32 + lgrp * 8]);
    #pragma unroll
    for (int n = 0; n < 2; ++n)
      bfv[n] = *reinterpret_cast<const bf16x8*>(&sB[(wc * 32 + n * 16 + lane16) * 32 + lgrp * 8]);
    #pragma unroll
    for (int m = 0; m < 2; ++m)
      #pragma unroll
      for (int n = 0; n < 2; ++n)
        acc[m][n] = __builtin_amdgcn_mfma_f32_16x16x32_bf16(af[m], bfv[n], acc[m][n], 0, 0, 0);
  }

  #pragma unroll
  for (int m = 0; m < 2; ++m) {
    #pragma unroll
    for (int n = 0; n < 2; ++n) {
      int colg = bn + wc * 32 + n * 16 + lane16;
      float bv = bias[colg];
      #pragma unroll
      for (int e = 0; e < 4; ++e) {
        int rowg = bm + wr * 32 + m * 16 + lgrp * 4 + e;
        D[(size_t)rowg * HID + colg] = acc[m][n][e] + bv;
      }
    }
  }
}

// ---------------- MFMA sparse attention ----------------
__global__ __launch_bounds__(256)
void sparse_attn_mfma(const __hip_bfloat16* __restrict__ qg,
                      const __hip_bfloat16* __restrict__ kg,
                      const __hip_bfloat16* __restrict__ vg,
                      __hip_bfloat16* __restrict__ out)
{
  __shared__ __align__(16) unsigned short sKP[KR * KP];
  __shared__ __align__(16) unsigned short sVT[HD * VP];

  const int tid = threadIdx.x;
  const int w   = tid >> 6, lane = tid & 63;
  const int l16 = lane & 15, lg = lane >> 4;
  const int bid = blockIdx.x;
  const int bh  = bid >> 5;
  const int qb  = bid & 31;
  const int i0  = qb * QB;

  const __hip_bfloat16* qh = qg + (size_t)bh * Sq * HD;
  const __hip_bfloat16* kh = kg + (size_t)bh * Sq * HD;
  const __hip_bfloat16* vh = vg + (size_t)bh * Sq * HD;

  #pragma unroll
  for (int p = 0; p < 10; ++p) {
    int c  = p * 256 + tid;
    int r  = c >> 4, d4 = (c & 15) * 4;
    int j  = (r < 128) ? (i0 - 64 + r) : ((r == 128) ? 0 : -1);
    ushort4 kv = {0, 0, 0, 0}, vv = {0, 0, 0, 0};
    if (j >= 0) {
      kv = *reinterpret_cast<const ushort4*>(kh + (size_t)j * HD + d4);
      vv = *reinterpret_cast<const ushort4*>(vh + (size_t)j * HD + d4);
    }
    *reinterpret_cast<ushort4*>(&sKP[r * KP + d4]) = kv;
    sVT[(d4 + 0) * VP + r] = vv.x;
    sVT[(d4 + 1) * VP + r] = vv.y;
    sVT[(d4 + 2) * VP + r] = vv.z;
    sVT[(d4 + 3) * VP + r] = vv.w;
  }
  __syncthreads();

  const int qi0 = w * 16;
  bf16x8 aq[2];
  #pragma unroll
  for (int ks = 0; ks < 2; ++ks)
    aq[ks] = *reinterpret_cast<const bf16x8*>(qh + (size_t)(i0 + qi0 + l16) * HD + ks * 32 + lg * 8);

  f32x4 c[10];
  #pragma unroll
  for (int n = 0; n < 10; ++n) {
    c[n] = (f32x4){0.f, 0.f, 0.f, 0.f};
    #pragma unroll
    for (int ks = 0; ks < 2; ++ks) {
      bf16x8 bk = *reinterpret_cast<const bf16x8*>(&sKP[(n * 16 + l16) * KP + ks * 32 + lg * 8]);
      c[n] = __builtin_amdgcn_mfma_f32_16x16x32_bf16(aq[ks], bk, c[n], 0, 0, 0);
    }
  }

  float p[10][4];
  float mx[4], sm[4], inv[4];
  #pragma unroll
  for (int e = 0; e < 4; ++e) mx[e] = -INFINITY;
  #pragma unroll
  for (int n = 0; n < 10; ++n) {
    int r = n * 16 + l16;
    int jg = i0 - 64 + r;
    #pragma unroll
    for (int e = 0; e < 4; ++e) {
      int qi = qi0 + lg * 4 + e;
      bool ok = (n < 8) ? (r >= qi && r <= qi + 64 && jg >= 0)
                        : (r == 128 && (i0 + qi) > 64);
      float sv = ok ? c[n][e] * 0.125f : -INFINITY;
      p[n][e] = sv;
      mx[e] = fmaxf(mx[e], sv);
    }
  }
  #pragma unroll
  for (int off = 1; off < 16; off <<= 1)
    #pragma unroll
    for (int e = 0; e < 4; ++e)
      mx[e] = fmaxf(mx[e], __shfl_xor(mx[e], off));
  #pragma unroll
  for (int e = 0; e < 4; ++e) sm[e] = 0.f;
  #pragma unroll
  for (int n = 0; n < 10; ++n)
    #pragma unroll
    for (int e = 0; e < 4; ++e) {
      float pe = __expf(p[n][e] - mx[e]);
      p[n][e] = pe;
      sm[e] += pe;
    }
  #pragma unroll
  for (int off = 1; off < 16; off <<= 1)
    #pragma unroll
    for (int e = 0; e < 4; ++e)
      sm[e] += __shfl_xor(sm[e], off);
  #pragma unroll
  for (int e = 0; e < 4; ++e) inv[e] = 1.f / sm[e];

  __syncthreads();
  unsigned short* Pw = &sKP[w * 16 * VP];
  #pragma unroll
  for (int n = 0; n < 10; ++n)
    #pragma unroll
    for (int e = 0; e < 4; ++e) {
      __hip_bfloat16 hb = __float2bfloat16(p[n][e] * inv[e]);
      Pw[(lg * 4 + e) * VP + n * 16 + l16] = *reinterpret_cast<unsigned short*>(&hb);
    }

  f32x4 o[4];
  #pragma unroll
  for (int n = 0; n < 4; ++n) o[n] = (f32x4){0.f, 0.f, 0.f, 0.f};
  #pragma unroll
  for (int ks = 0; ks < 5; ++ks) {
    bf16x8 pa = *reinterpret_cast<const bf16x8*>(&Pw[l16 * VP + ks * 32 + lg * 8]);
    #pragma unroll
    for (int n = 0; n < 4; ++n) {
      bf16x8 vb = *reinterpret_cast<const bf16x8*>(&sVT[(n * 16 + l16) * VP + ks * 32 + lg * 8]);
      o[n] = __builtin_amdgcn_mfma_f32_16x16x32_bf16(pa, vb, o[n], 0, 0, 0);
    }
  }

  const int b = bh >> 4, h = bh & 15;
  #pragma unroll
  for (int e = 0; e < 4; ++e) {
    int i = i0 + qi0 + lg * 4 + e;
    size_t base = ((size_t)(b * Sq + i)) * HID + h * HD;
    #pragma unroll
    for (int n = 0; n < 4; ++n)
      out[base + n * 16 + l16] = __float2bfloat16(o[n][e]);
  }
}

// ---------------- launch ----------------
extern "C" void kernel_launch(void* const* d_in, const int* in_sizes, int n_in,
                              void* d_out, int out_size, void* d_ws, size_t ws_size,
                              hipStream_t stream) {
  const float* hs = (const float*)d_in[0];
  const float* Wq = (const float*)d_in[1];
  const float* bq = (const float*)d_in[2];
  const float* Wk = (const float*)d_in[3];
  const float* bk = (const float*)d_in[4];
  const float* Wv = (const float*)d_in[5];
  const float* bv = (const float*)d_in[6];
  const float* Wo = (const float*)d_in[7];
  const float* bo = (const float*)d_in[8];

  char* ws = (char*)d_ws;
  __hip_bfloat16* Xbf = (__hip_bfloat16*)(ws);                 //  8 MB
  __hip_bfloat16* Wqb = (__hip_bfloat16*)(ws +  8388608);      //  2 MB
  __hip_bfloat16* Wkb = (__hip_bfloat16*)(ws + 10485760);      //  2 MB
  __hip_bfloat16* Wvb = (__hip_bfloat16*)(ws + 12582912);      //  2 MB
  __hip_bfloat16* Wob = (__hip_bfloat16*)(ws + 14680064);      //  2 MB
  __hip_bfloat16* qb  = (__hip_bfloat16*)(ws + 16777216);      //  8 MB
  __hip_bfloat16* kb  = (__hip_bfloat16*)(ws + 25165824);      //  8 MB
  __hip_bfloat16* vb_ = (__hip_bfloat16*)(ws + 33554432);      //  8 MB
  __hip_bfloat16* att = (__hip_bfloat16*)(ws + 41943040);      //  8 MB  (total 50 MB)

  // one fused cast launch (hs + 4 weights)
  cast_all_k<<<8192, 256, 0, stream>>>(hs, Wq, Wk, Wv, Wo, Xbf, Wqb, Wkb, Wvb, Wob);

  // fused QKV projection -> bf16 [B,H,S,D]
  dim3 g1(3 * HID / 128, (Bsz * Sq) / 128);
  gemm_qkv<<<g1, 256, 0, stream>>>(Xbf, Wqb, Wkb, Wvb, bq, bk, bv, qb, kb, vb_, HID);

  // MFMA sparse attention
  sparse_attn_mfma<<<Bsz * NH * (Sq / QB), 256, 0, stream>>>(qb, kb, vb_, att);

  // output projection (64x64 tiles, 1024 blocks) -> fp32 d_out
  dim3 g2(HID / 64, (Bsz * Sq) / 64);
  gemm_o64<<<g2, 256, 0, stream>>>(att, Wob, bo, (float*)d_out, HID);
}